// Round 10
// baseline (260.555 us; speedup 1.0000x reference)
//
#include <hip/hip_runtime.h>

// DIAGNOSTIC ROUND (R10). R4-R9 all pinned at 63-75us, MfmaUtil~30%,
// VALUBusy~30%, ~40% of wall with no pipe issuing. Ablation per skill rule
// "ablate before optimizing":
//  1) rbf_kern<true>  = R5 kernel verbatim (real, writes d_out)  ~64-68us
//  2) rbf_kern<false> = same minus exp2 (inferred from headline sum)
//  3) abl_mfma        = pure 24-MFMA/tile loop, 2 chains/wave, x4 sweeps,
//                       no loads/epi -> visible as slowest dispatch WITH its
//                       MfmaUtil. Healthy: ~83us @ ~100% util. Chain-latency
//                       bound: >=130us @ 30-60% util.

typedef __attribute__((ext_vector_type(8))) short short8v;
typedef __attribute__((ext_vector_type(16))) float f32x16;
typedef unsigned short u16;
typedef unsigned int u32;

#define L2E   1.4426950408889634f
#define NHL2E 0.72134752044448170f   // log2(e)/2
#define GSPLIT 8

__device__ __forceinline__ u16 f2bf(float x){
  u32 u = __float_as_uint(x);
  return (u16)((u + 0x7FFFu + ((u >> 16) & 1u)) >> 16);   // RNE
}
__device__ __forceinline__ float bf2f(u16 h){ return __uint_as_float(((u32)h) << 16); }

#define MFMA(a,b,c) __builtin_amdgcn_mfma_f32_32x32x16_bf16(a,b,c,0,0,0)

// ---- one-time: C [G][64] fp32 -> hi/lo bf16 in fragment order + (cn,w) ----
__global__ __launch_bounds__(256)
void convert_C(const float* __restrict__ C, const float* __restrict__ W,
               u16* __restrict__ Chi, u16* __restrict__ Clo,
               float2* __restrict__ cw, int G){
  int idx = blockIdx.x*256 + threadIdx.x;
  int g = idx >> 2, f = idx & 3;
  if (g >= G) return;
  const float* row = C + (size_t)g*64 + f*16;
  int cg = g >> 5, cl = g & 31;
  float norm = 0.f;
  u16 hb[16], lb[16];
  #pragma unroll
  for (int q=0; q<4; q++){
    float4 v = *(const float4*)(row + q*4);
    float xv[4] = {v.x, v.y, v.z, v.w};
    #pragma unroll
    for (int e=0; e<4; e++){
      float x = xv[e];
      norm = fmaf(x, x, norm);
      u16 hh = f2bf(x); hb[q*4+e] = hh;
      lb[q*4+e] = f2bf(x - bf2f(hh));
    }
  }
  norm += __shfl_xor(norm, 1);
  norm += __shfl_xor(norm, 2);
  size_t u = ((size_t)(cg*4 + f)*64 + cl)*8;
  *(short8v*)(Chi + u)        = *(short8v*)hb;
  *(short8v*)(Chi + u + 256)  = *(short8v*)(hb + 8);
  *(short8v*)(Clo + u)        = *(short8v*)lb;
  *(short8v*)(Clo + u + 256)  = *(short8v*)(lb + 8);
  if (f == 0) cw[g] = make_float2(-NHL2E*norm, W[g]);
}

// ================= R5 kernel, templated on WITH_EXP ==================
template<bool WITH_EXP>
__global__ __launch_bounds__(256, 2)
void rbf_kern(const float* __restrict__ X, const u16* __restrict__ Chi,
              const u16* __restrict__ Clo, const float2* __restrict__ cw,
              float* __restrict__ outp){
  const int tid = threadIdx.x;
  const int l  = tid & 63;
  const int cl = l & 31;
  const int h  = l >> 5;
  const int w  = tid >> 6;
  const int b  = blockIdx.x;
  const int gp = b & 7;
  const int rows0 = ((b >> 3)*4 + w) * 64;

  short8v ah[2][4], al[2][4];
  float xn[2];
  #pragma unroll
  for (int rf=0; rf<2; rf++){
    const float* xr = X + (size_t)(rows0 + rf*32 + cl)*64;
    float s = 0.f;
    #pragma unroll
    for (int f=0; f<4; f++){
      float4 v0 = *(const float4*)(xr + f*16 + h*8);
      float4 v1 = *(const float4*)(xr + f*16 + h*8 + 4);
      float xv[8] = {v0.x,v0.y,v0.z,v0.w,v1.x,v1.y,v1.z,v1.w};
      u16 hb[8], lb[8];
      #pragma unroll
      for (int e=0;e<8;e++){
        float x = xv[e];
        s = fmaf(x, x, s);
        u16 hh = f2bf(x); hb[e]=hh;
        lb[e] = f2bf(x - bf2f(hh));
      }
      ah[rf][f] = *(short8v*)hb;
      al[rf][f] = *(short8v*)lb;
    }
    s += __shfl_xor(s, 32);
    xn[rf] = -NHL2E * s;
  }

  const char* baseH = (const char*)Chi + (size_t)gp*131072 + (size_t)l*16;
  const char* baseL = (const char*)Clo + (size_t)gp*131072 + (size_t)l*16;
  const float2* cwp = cw + gp*1024 + cl;

  short8v bh[2], bl[2];
  bh[0] = *(const short8v*)baseH;
  bl[0] = *(const short8v*)baseL;

  float racc0[16], racc1[16];
  #pragma unroll
  for (int r=0;r<16;r++){ racc0[r]=0.f; racc1[r]=0.f; }

  f32x16 aE0, aE1, aO0, aO1;
  float2 cwE, cwO;

  #define MSTEP(T, A0, A1, CWR) do {                                        \
    const int t_ = (T);                                                     \
    CWR = cwp[t_*32];                                                       \
    A0 = (f32x16){}; A1 = (f32x16){};                                       \
    __builtin_amdgcn_s_setprio(1);                                          \
    _Pragma("unroll")                                                       \
    for (int f=0; f<4; ++f){                                                \
      const int p = f & 1, q = p ^ 1;                                       \
      const int nf = (f + 1) & 3;                                           \
      const int nt = (f == 3) ? ((t_ + 1) & 31) : t_;                       \
      const size_t off = (size_t)nt*4096 + (size_t)nf*1024;                 \
      bh[q] = *(const short8v*)(baseH + off);                               \
      bl[q] = *(const short8v*)(baseL + off);                               \
      A0 = MFMA(ah[0][f], bh[p], A0);                                       \
      A1 = MFMA(ah[1][f], bh[p], A1);                                       \
      A0 = MFMA(ah[0][f], bl[p], A0);                                       \
      A1 = MFMA(ah[1][f], bl[p], A1);                                       \
      A0 = MFMA(al[0][f], bh[p], A0);                                       \
      A1 = MFMA(al[1][f], bh[p], A1);                                       \
    }                                                                       \
    __builtin_amdgcn_s_setprio(0);                                          \
  } while(0)

  #define EPI(A0, A1, CWR) do {                                             \
    _Pragma("unroll")                                                       \
    for (int r=0;r<16;++r){                                                 \
      if (WITH_EXP){                                                        \
        racc0[r] = fmaf(__builtin_amdgcn_exp2f(fmaf(A0[r], L2E, CWR.x)),    \
                        CWR.y, racc0[r]);                                   \
        racc1[r] = fmaf(__builtin_amdgcn_exp2f(fmaf(A1[r], L2E, CWR.x)),    \
                        CWR.y, racc1[r]);                                   \
      } else {                                                              \
        racc0[r] = fmaf(fmaf(A0[r], L2E, CWR.x), CWR.y, racc0[r]);          \
        racc1[r] = fmaf(fmaf(A1[r], L2E, CWR.x), CWR.y, racc1[r]);          \
      }                                                                     \
    }                                                                       \
  } while(0)

  MSTEP(0, aE0, aE1, cwE);
  #pragma unroll 1
  for (int tp = 0; tp < 15; ++tp){
    MSTEP(2*tp + 1, aO0, aO1, cwO);
    EPI(aE0, aE1, cwE);
    MSTEP(2*tp + 2, aE0, aE1, cwE);
    EPI(aO0, aO1, cwO);
  }
  MSTEP(31, aO0, aO1, cwO);
  EPI(aE0, aE1, cwE);
  EPI(aO0, aO1, cwO);
  #undef MSTEP
  #undef EPI

  #pragma unroll
  for (int rf=0; rf<2; rf++){
    #pragma unroll
    for (int r=0;r<16;r++){
      float v = rf ? racc1[r] : racc0[r];
      v += __shfl_xor(v, 1);
      v += __shfl_xor(v, 2);
      v += __shfl_xor(v, 4);
      v += __shfl_xor(v, 8);
      v += __shfl_xor(v, 16);
      const int rit = (r&3) + 8*(r>>2) + 4*h;
      const float xnv = __shfl(xn[rf], rit);
      if (cl == 0)
        atomicAdd(&outp[rows0 + rf*32 + rit], v * __builtin_amdgcn_exp2f(xnv));
    }
  }
}

// ============ ablation: pure MFMA loop, 2 chains/wave, x4 sweeps ============
__global__ __launch_bounds__(256, 2)
void abl_mfma(const u16* __restrict__ Chi, float* __restrict__ wsout){
  const int l = threadIdx.x & 63;

  short8v ah[2][4], al[2][4];
  #pragma unroll
  for (int rf=0; rf<2; rf++)
    #pragma unroll
    for (int f=0; f<4; f++){
      u16 hv = f2bf(0.01f*(f+1) + 0.001f*rf);
      u16 lv = f2bf(0.0001f*((l&7)+1));
      u16 t0[8], t1[8];
      #pragma unroll
      for (int e=0;e<8;e++){ t0[e]=hv; t1[e]=lv; }
      ah[rf][f] = *(short8v*)t0;
      al[rf][f] = *(short8v*)t1;
    }
  short8v bh = *(const short8v*)(Chi + (size_t)l*8);
  short8v bl = *(const short8v*)(Chi + 512 + (size_t)l*8);

  float racc0[16], racc1[16];
  #pragma unroll
  for (int r=0;r<16;r++){ racc0[r]=0.f; racc1[r]=0.f; }

  #pragma unroll 1
  for (int s=0; s<4; ++s){
    #pragma unroll 1
    for (int t=0; t<32; ++t){
      // defeat LICM/CSE across tiles: perturb one bf16 element per buffer
      bh[0] = (short)(t + s);
      bl[0] = (short)(t ^ 5);
      f32x16 a0 = {}, a1 = {};
      #pragma unroll
      for (int f=0; f<4; ++f){
        a0 = MFMA(ah[0][f], bh, a0);
        a1 = MFMA(ah[1][f], bh, a1);
        a0 = MFMA(ah[0][f], bl, a0);
        a1 = MFMA(ah[1][f], bl, a1);
        a0 = MFMA(al[0][f], bh, a0);
        a1 = MFMA(al[1][f], bh, a1);
      }
      #pragma unroll
      for (int r=0;r<16;++r){ racc0[r]+=a0[r]; racc1[r]+=a1[r]; }
    }
  }
  float s0 = 0.f;
  #pragma unroll
  for (int r=0;r<16;++r) s0 += racc0[r] + racc1[r];
  atomicAdd(&wsout[l], s0);
}

extern "C" void kernel_launch(void* const* d_in, const int* in_sizes, int n_in,
                              void* d_out, int out_size, void* d_ws, size_t ws_size,
                              hipStream_t stream) {
  const float* X = (const float*)d_in[0];   // [B,64]
  const float* C = (const float*)d_in[1];   // [G,64]
  const float* W = (const float*)d_in[2];   // [G]
  float* out = (float*)d_out;               // [B]
  const int B = in_sizes[0] / 64;
  const int G = in_sizes[2];

  u16* Chi = (u16*)d_ws;                         // 1 MB
  u16* Clo = Chi + (size_t)G*64;                 // 1 MB
  float2* cw = (float2*)(Clo + (size_t)G*64);    // 64 KB
  float* wsout = (float*)(cw + G);               // junk sink for ablations

  hipMemsetAsync(out, 0, (size_t)B*sizeof(float), stream);
  convert_C<<<(G*4)/256, 256, 0, stream>>>(C, W, Chi, Clo, cw, G);

  const int grid = (B/256)*GSPLIT;               // 512
  rbf_kern<true ><<<grid, 256, 0, stream>>>(X, Chi, Clo, cw, out);    // real
  rbf_kern<false><<<grid, 256, 0, stream>>>(X, Chi, Clo, cw, wsout);  // -exp2
  abl_mfma<<<grid, 256, 0, stream>>>(Chi, wsout);                     // pure MFMA x4
}

// Round 12
// 67.152 us; speedup vs baseline: 3.8801x; 3.8801x over previous
//
#include <hip/hip_runtime.h>

// out[b] = sum_g exp(-(||x_b||^2+||c_g||^2-2 x_b.c_g)/2) * w[g]
// B=16384, G=8192, D=64 fp32.
// v12 = BISECT of v11's correctness failure. v11 deltas vs passing v5/v10:
//  (a) EPI interleaved between MFMAs (E/O acc sets)   -> KEPT
//  (b) setprio removed                                 -> KEPT
//  (c) sched_group_barrier pattern                     -> REMOVED (suspect)
//  (d) convert_C zeroes out / no memset                -> REVERTED
// Logic of (a) hand-verified (WAR-free, exactly-once EPI, ping-pong
// invariant); if this round still fails numerically the interleave is
// miscompiled and v13 reverts to v5 + producer/consumer waves.

typedef __attribute__((ext_vector_type(8))) short short8v;
typedef __attribute__((ext_vector_type(16))) float f32x16;
typedef unsigned short u16;
typedef unsigned int u32;

#define L2E   1.4426950408889634f
#define NHL2E 0.72134752044448170f   // log2(e)/2
#define GSPLIT 8

__device__ __forceinline__ u16 f2bf(float x){
  u32 u = __float_as_uint(x);
  return (u16)((u + 0x7FFFu + ((u >> 16) & 1u)) >> 16);   // RNE
}
__device__ __forceinline__ float bf2f(u16 h){ return __uint_as_float(((u32)h) << 16); }

#define MFMA(a,b,c) __builtin_amdgcn_mfma_f32_32x32x16_bf16(a,b,c,0,0,0)

// ---- one-time: C [G][64] fp32 -> hi/lo bf16 in fragment order + (cn,w) ----
// (identical to the R10-passing version)
__global__ __launch_bounds__(256)
void convert_C(const float* __restrict__ C, const float* __restrict__ W,
               u16* __restrict__ Chi, u16* __restrict__ Clo,
               float2* __restrict__ cw, int G){
  int idx = blockIdx.x*256 + threadIdx.x;
  int g = idx >> 2, f = idx & 3;
  if (g >= G) return;
  const float* row = C + (size_t)g*64 + f*16;
  int cg = g >> 5, cl = g & 31;
  float norm = 0.f;
  u16 hb[16], lb[16];
  #pragma unroll
  for (int q=0; q<4; q++){
    float4 v = *(const float4*)(row + q*4);
    float xv[4] = {v.x, v.y, v.z, v.w};
    #pragma unroll
    for (int e=0; e<4; e++){
      float x = xv[e];
      norm = fmaf(x, x, norm);
      u16 hh = f2bf(x); hb[q*4+e] = hh;
      lb[q*4+e] = f2bf(x - bf2f(hh));
    }
  }
  norm += __shfl_xor(norm, 1);
  norm += __shfl_xor(norm, 2);
  size_t u = ((size_t)(cg*4 + f)*64 + cl)*8;
  *(short8v*)(Chi + u)        = *(short8v*)hb;        // h=0 (k 0..7)
  *(short8v*)(Chi + u + 256)  = *(short8v*)(hb + 8);  // h=1 (k 8..15)
  *(short8v*)(Clo + u)        = *(short8v*)lb;
  *(short8v*)(Clo + u + 256)  = *(short8v*)(lb + 8);
  if (f == 0) cw[g] = make_float2(-NHL2E*norm, W[g]);
}

__global__ __launch_bounds__(256, 2)
void rbf_mfma(const float* __restrict__ X, const u16* __restrict__ Chi,
              const u16* __restrict__ Clo, const float2* __restrict__ cw,
              float* __restrict__ out){
  const int tid = threadIdx.x;
  const int l  = tid & 63;
  const int cl = l & 31;
  const int h  = l >> 5;
  const int w  = tid >> 6;
  const int b  = blockIdx.x;
  const int gp = b & 7;                  // 4 waves share gp -> L1/L2 B-sharing
  const int rows0 = ((b >> 3)*4 + w) * 64;

  // ---- A: 64 rows (2 rowfrags) hi/lo bf16 in registers ----
  short8v ah[2][4], al[2][4];
  float xn[2];
  #pragma unroll
  for (int rf=0; rf<2; rf++){
    const float* xr = X + (size_t)(rows0 + rf*32 + cl)*64;
    float s = 0.f;
    #pragma unroll
    for (int f=0; f<4; f++){
      float4 v0 = *(const float4*)(xr + f*16 + h*8);
      float4 v1 = *(const float4*)(xr + f*16 + h*8 + 4);
      float xv[8] = {v0.x,v0.y,v0.z,v0.w,v1.x,v1.y,v1.z,v1.w};
      u16 hb[8], lb[8];
      #pragma unroll
      for (int e=0;e<8;e++){
        float x = xv[e];
        s = fmaf(x, x, s);
        u16 hh = f2bf(x); hb[e]=hh;
        lb[e] = f2bf(x - bf2f(hh));
      }
      ah[rf][f] = *(short8v*)hb;
      al[rf][f] = *(short8v*)lb;
    }
    s += __shfl_xor(s, 32);
    xn[rf] = -NHL2E * s;
  }

  // B stream: byte addr = t*4096 + f*1024 + l*16 within this gp part
  const char* baseH = (const char*)Chi + (size_t)gp*131072 + (size_t)l*16;
  const char* baseL = (const char*)Clo + (size_t)gp*131072 + (size_t)l*16;
  const float2* cwp = cw + gp*1024 + cl;

  short8v bh[2], bl[2];
  bh[0] = *(const short8v*)baseH;        // (t=0, f=0)
  bl[0] = *(const short8v*)baseL;

  float racc0[16], racc1[16];
  #pragma unroll
  for (int r=0;r<16;r++){ racc0[r]=0.f; racc1[r]=0.f; }

  f32x16 aE0, aE1, aO0, aO1;
  float2 cwE, cwO;

  // one epilogue element: RACC[R] += 2^(L2E*P[R] + CWV.x) * CWV.y
  #define EPIX(P, R, CWV, RACC)                                             \
    RACC[R] = fmaf(__builtin_amdgcn_exp2f(fmaf(P[R], L2E, CWV.x)),          \
                   CWV.y, RACC[R])

  // tile T: MFMAs into (C0,C1); EPI of prev tile (P0,P1) interleaved 2 exps
  // per MFMA; B depth-1 ping-pong. NO sched_group_barrier, NO setprio.
  #define TILE(T, C0, C1, P0, P1, CWC, CWP, DO_EPI) do {                    \
    const int t_ = (T);                                                     \
    CWC = cwp[t_*32];                                                       \
    C0 = (f32x16){}; C1 = (f32x16){};                                       \
    _Pragma("unroll")                                                       \
    for (int f=0; f<4; ++f){                                                \
      const int p = f & 1, q = p ^ 1;                                       \
      const int nf = (f + 1) & 3;                                           \
      const int nt = (f == 3) ? ((t_ + 1) & 31) : t_;                       \
      const size_t off = (size_t)nt*4096 + (size_t)nf*1024;                 \
      bh[q] = *(const short8v*)(baseH + off);                               \
      bl[q] = *(const short8v*)(baseL + off);                               \
      C0 = MFMA(ah[0][f], bh[p], C0);                                       \
      if (DO_EPI){ EPIX(P0, f*4+0, CWP, racc0); EPIX(P1, f*4+0, CWP, racc1);} \
      C1 = MFMA(ah[1][f], bh[p], C1);                                       \
      if (DO_EPI){ EPIX(P0, f*4+1, CWP, racc0); EPIX(P1, f*4+1, CWP, racc1);} \
      C0 = MFMA(ah[0][f], bl[p], C0);                                       \
      if (DO_EPI){ EPIX(P0, f*4+2, CWP, racc0); EPIX(P1, f*4+2, CWP, racc1);} \
      C1 = MFMA(ah[1][f], bl[p], C1);                                       \
      if (DO_EPI){ EPIX(P0, f*4+3, CWP, racc0); EPIX(P1, f*4+3, CWP, racc1);} \
      C0 = MFMA(al[0][f], bh[p], C0);                                       \
      C1 = MFMA(al[1][f], bh[p], C1);                                       \
    }                                                                       \
  } while(0)

  TILE(0, aE0, aE1, aO0, aO1, cwE, cwO, 0);     // prologue: no EPI yet
  #pragma unroll 1
  for (int tp = 0; tp < 15; ++tp){
    TILE(2*tp + 1, aO0, aO1, aE0, aE1, cwO, cwE, 1);
    TILE(2*tp + 2, aE0, aE1, aO0, aO1, cwE, cwO, 1);
  }
  TILE(31, aO0, aO1, aE0, aE1, cwO, cwE, 1);    // EPIs tile 30
  #pragma unroll
  for (int r=0;r<16;++r){                       // final EPI: tile 31
    EPIX(aO0, r, cwO, racc0);
    EPIX(aO1, r, cwO, racc1);
  }
  #undef TILE
  #undef EPIX

  // ---- reduce over 32 col-lanes, fold 2^xn, one atomic per row ----
  #pragma unroll
  for (int rf=0; rf<2; rf++){
    #pragma unroll
    for (int r=0;r<16;r++){
      float v = rf ? racc1[r] : racc0[r];
      v += __shfl_xor(v, 1);
      v += __shfl_xor(v, 2);
      v += __shfl_xor(v, 4);
      v += __shfl_xor(v, 8);
      v += __shfl_xor(v, 16);
      const int rit = (r&3) + 8*(r>>2) + 4*h;
      const float xnv = __shfl(xn[rf], rit);
      if (cl == 0)
        atomicAdd(&out[rows0 + rf*32 + rit], v * __builtin_amdgcn_exp2f(xnv));
    }
  }
}

extern "C" void kernel_launch(void* const* d_in, const int* in_sizes, int n_in,
                              void* d_out, int out_size, void* d_ws, size_t ws_size,
                              hipStream_t stream) {
  const float* X = (const float*)d_in[0];   // [B,64]
  const float* C = (const float*)d_in[1];   // [G,64]
  const float* W = (const float*)d_in[2];   // [G]
  float* out = (float*)d_out;               // [B]
  const int B = in_sizes[0] / 64;
  const int G = in_sizes[2];

  u16* Chi = (u16*)d_ws;                         // 1 MB
  u16* Clo = Chi + (size_t)G*64;                 // 1 MB
  float2* cw = (float2*)(Clo + (size_t)G*64);    // 64 KB

  hipMemsetAsync(out, 0, (size_t)B*sizeof(float), stream);
  convert_C<<<(G*4)/256, 256, 0, stream>>>(C, W, Chi, Clo, cw, G);
  rbf_mfma<<<(B/256)*GSPLIT, 256, 0, stream>>>(X, Chi, Clo, cw, out);
}